// Round 21
// baseline (225.994 us; speedup 1.0000x reference)
//
#include <hip/hip_runtime.h>
#include <math.h>

#define B_ 4
#define N_ 4096
#define KP 512
#define C_ 384

typedef unsigned short u16;
typedef short s8v __attribute__((ext_vector_type(8)));
typedef float f4v __attribute__((ext_vector_type(4)));
#define MFMA(a,b,c) __builtin_amdgcn_mfma_f32_16x16x32_bf16(a,b,c,0,0,0)

constexpr float TAU_INV  = 10.0f;
constexpr float BETA_    = 0.85f;
constexpr float JITTER_  = 1e-6f;
constexpr float ALPHA_   = 1.5f;
constexpr float SFLOOR_  = 1e-3f;
constexpr float SCEIL_   = 100.0f;
constexpr float MU_SCALE_= 0.25f;
constexpr float NEGV     = -1e9f;
constexpr float BIG_     = 1e9f;

__device__ __forceinline__ u16 f2b_rne(float f) {
  unsigned int u = __float_as_uint(f);
  return (u16)((u + 0x7FFFu + ((u >> 16) & 1u)) >> 16);
}
__device__ __forceinline__ float b2f(u16 h) {
  return __uint_as_float(((unsigned int)h) << 16);
}
__device__ __forceinline__ void split_hl(float f, u16& hi, u16& lo) {
  unsigned int u = __float_as_uint(f);
  hi = (u16)(u >> 16);
  float fh = __uint_as_float(u & 0xFFFF0000u);
  lo = f2b_rne(f - fh);
}

// Packed fragment layouts (per 16x16x32 MFMA), 1KB contiguous per fragment:
//  K (A-op):   [b*32+kp_tile][cc(12)][lane][8], lane=(kp&15)+16*((c>>3)&3)
//  q (B-op):   [n>>4][cc(12)][lane][8],        lane=(n&15)+16*((c>>3)&3)
//  V^T/spT (B-op): [b*24+c_tile][ks(16)][lane][8], lane=(c&15)+16*((kp>>3)&3)
//  W (B-op):   [ot(24)][cs(12)][lane][8],      lane=(outc&15)+16*((inc>>3)&3)
//  musig (B-op): [b][ks(16)][lane][8], cols 0-2=mu, 3-11=symSig, 12-15=0

// ---------------- device helper: pack one W ot-tile ----------------
__device__ __forceinline__ void wpack_body(
    const float* __restrict__ W, u16* __restrict__ whi, u16* __restrict__ wlo,
    int ot, int t) {
  for (int s = t; s < 768; s += 256) {
    int cs = s >> 6, lane = s & 63;
    int outc = ot*16 + (lane & 15);
    int inc0 = cs*32 + (lane >> 4)*8;
    u16 hh[8], ll[8];
    #pragma unroll
    for (int e = 0; e < 8; ++e)
      split_hl(W[(size_t)outc*C_ + inc0 + e], hh[e], ll[e]);
    size_t fo = ((size_t)ot*12 + cs)*512 + (size_t)lane*8;
    *(ushort4*)&whi[fo]   = make_ushort4(hh[0],hh[1],hh[2],hh[3]);
    *(ushort4*)&whi[fo+4] = make_ushort4(hh[4],hh[5],hh[6],hh[7]);
    if (wlo) {
      *(ushort4*)&wlo[fo]   = make_ushort4(ll[0],ll[1],ll[2],ll[3]);
      *(ushort4*)&wlo[fo+4] = make_ushort4(ll[4],ll[5],ll[6],ll[7]);
    }
  }
}

// ---------------- K0: merged prep: wpack(Wq,Wk,Wv,W1) + sptr + musig ----------------
__global__ __launch_bounds__(256) void k_prep(
    const float* __restrict__ Wq, const float* __restrict__ Wk,
    const float* __restrict__ Wv, const float* __restrict__ W1,
    const float* __restrict__ sp, const float* __restrict__ mu_p,
    const float* __restrict__ Sig_p,
    u16* __restrict__ wqhi, u16* __restrict__ wqlo,
    u16* __restrict__ wkhi, u16* __restrict__ wklo,
    u16* __restrict__ wvhi,
    u16* __restrict__ w1hi,
    u16* __restrict__ spt,
    u16* __restrict__ mshi) {
  __shared__ float tl[32][33];
  int blk = blockIdx.x;
  int t = threadIdx.x;
  if (blk < 96) {
    int which = blk / 24, ot = blk % 24;
    if (which == 0)      wpack_body(Wq, wqhi, wqlo, ot, t);
    else if (which == 1) wpack_body(Wk, wkhi, wklo, ot, t);
    else if (which == 2) wpack_body(Wv, wvhi, (u16*)0, ot, t);
    else                 wpack_body(W1, w1hi, (u16*)0, ot, t);
  } else if (blk < 864) {
    int u = blk - 96;
    int bz = u / 192, rem = u % 192;
    int by = (rem / 16) * 32;   // c
    int bx = (rem % 16) * 32;   // kp
    const float* s = sp + (size_t)bz * KP * C_;
    int tx = t & 31, ty4 = t >> 5;
    #pragma unroll
    for (int j = 0; j < 32; j += 8)
      tl[ty4 + j][tx] = s[(size_t)(bx + ty4 + j) * C_ + by + tx];
    __syncthreads();
    if (t < 128) {
      int c_l = t >> 2, krun = t & 3;
      int kp0r = krun * 8;
      u16 hh[8];
      #pragma unroll
      for (int e = 0; e < 8; ++e) hh[e] = f2b_rne(tl[kp0r + e][c_l]);
      int cg = by + c_l;
      int lane = (cg & 15) + 16 * krun;
      size_t fo = (((size_t)bz*24 + (cg >> 4))*16 + (bx >> 5))*512 + (size_t)lane*8;
      *(ushort4*)&spt[fo]   = make_ushort4(hh[0],hh[1],hh[2],hh[3]);
      *(ushort4*)&spt[fo+4] = make_ushort4(hh[4],hh[5],hh[6],hh[7]);
    }
  } else {
    int b = blk - 864;
    for (int s = t; s < 1024; s += 256) {
      int ks = s >> 6, lane = s & 63;
      int col = lane & 15, kb = lane >> 4;
      u16 hh[8];
      #pragma unroll
      for (int e = 0; e < 8; ++e) {
        int kp = ks*32 + kb*8 + e;
        float v = 0.f;
        if (col < 3) {
          v = mu_p[((size_t)b*KP + kp)*3 + col];
        } else if (col < 12) {
          int ee = col - 3, ii = ee/3, jj = ee%3;
          const float* sg = &Sig_p[((size_t)b*KP + kp)*9];
          v = 0.5f*(sg[ii*3+jj] + sg[jj*3+ii]);
        }
        hh[e] = f2b_rne(v);
      }
      size_t fo = (((size_t)b*16 + ks)*64 + lane)*8;
      *(ushort4*)&mshi[fo]   = make_ushort4(hh[0],hh[1],hh[2],hh[3]);
      *(ushort4*)&mshi[fo+4] = make_ushort4(hh[4],hh[5],hh[6],hh[7]);
    }
  }
}

// ---------------- K1: merged kvproj (blocks 0..127) + qproj 32-row (128..639) ----------------
__global__ __launch_bounds__(256) void k_kq(
    const float* __restrict__ sp, const float* __restrict__ mu_p,
    const float* __restrict__ gk, const float* __restrict__ bk,
    const float* __restrict__ gv, const float* __restrict__ bv,
    const u16* __restrict__ wkhi, const u16* __restrict__ wklo,
    const u16* __restrict__ wvhi,
    const float* __restrict__ Wpos,
    u16* __restrict__ khi, u16* __restrict__ klo,
    u16* __restrict__ vthi,
    const float* __restrict__ st, const float* __restrict__ gq,
    const float* __restrict__ bq,
    const u16* __restrict__ wqhi, const u16* __restrict__ wqlo,
    u16* __restrict__ qhi, u16* __restrict__ qlo) {
  __shared__ u16 fr[4*6144];
  float* stage = (float*)fr;
  int t = threadIdx.x;
  if (blockIdx.x < 128) {
    // ======== kvproj body ========
    int kb = blockIdx.x;
    int pr0 = kb * 16;
    {
      int r = t >> 4, l = t & 15;
      const float* xr = sp + (size_t)(pr0 + r) * C_;
      float xv[24]; float s = 0.f;
      #pragma unroll
      for (int j = 0; j < 24; ++j) { xv[j] = xr[l + 16*j]; s += xv[j]; }
      #pragma unroll
      for (int m = 1; m < 16; m <<= 1) s += __shfl_xor(s, m);
      float mean = s * (1.0f/C_);
      float vs = 0.f;
      #pragma unroll
      for (int j = 0; j < 24; ++j) { float d = xv[j]-mean; vs += d*d; }
      #pragma unroll
      for (int m = 1; m < 16; m <<= 1) vs += __shfl_xor(vs, m);
      float rs = 1.0f / sqrtf(vs * (1.0f/C_) + 1e-5f);
      #pragma unroll
      for (int j = 0; j < 24; ++j) {
        int c = l + 16*j;
        float xc = (xv[j]-mean)*rs;
        int idx = (c >> 5)*512 + ((r & 15) + 16*((c >> 3) & 3))*8 + (c & 7);
        u16 h, lo_;
        split_hl(xc*gk[c] + bk[c], h, lo_);
        fr[idx] = h; fr[6144 + idx] = lo_;
        fr[12288 + idx] = f2b_rne(xc*gv[c] + bv[c]);
      }
    }
    __syncthreads();
    int wv_ = t >> 6, lane = t & 63;
    int l15 = lane & 15, l4 = lane >> 4;
    float mur[4][3];
    #pragma unroll
    for (int rr = 0; rr < 4; ++rr) {
      int prow = pr0 + l4*4 + rr;
      mur[rr][0] = mu_p[(size_t)prow*3+0];
      mur[rr][1] = mu_p[(size_t)prow*3+1];
      mur[rr][2] = mu_p[(size_t)prow*3+2];
    }
    f4v acc[6];
    #pragma unroll
    for (int i = 0; i < 6; ++i) acc[i] = (f4v){0.f,0.f,0.f,0.f};
    #pragma unroll 2
    for (int cs = 0; cs < 12; ++cs) {
      s8v ah = *(const s8v*)&fr[cs*512 + lane*8];
      s8v al = *(const s8v*)&fr[6144 + cs*512 + lane*8];
      #pragma unroll
      for (int o6 = 0; o6 < 6; ++o6) {
        int ot = wv_*6 + o6;
        s8v bh = *(const s8v*)&wkhi[((size_t)ot*12 + cs)*512 + lane*8];
        s8v bl = *(const s8v*)&wklo[((size_t)ot*12 + cs)*512 + lane*8];
        acc[o6] = MFMA(ah, bh, acc[o6]);
        acc[o6] = MFMA(al, bh, acc[o6]);
        acc[o6] = MFMA(ah, bl, acc[o6]);
      }
    }
    #pragma unroll
    for (int o6 = 0; o6 < 6; ++o6) {
      int outc = (wv_*6 + o6)*16 + l15;
      float w0 = Wpos[outc*3+0], w1 = Wpos[outc*3+1], w2 = Wpos[outc*3+2];
      #pragma unroll
      for (int rr = 0; rr < 4; ++rr)
        acc[o6][rr] += mur[rr][0]*w0 + mur[rr][1]*w1 + mur[rr][2]*w2;
    }
    __syncthreads();
    #pragma unroll
    for (int o6 = 0; o6 < 6; ++o6) {
      int c = (wv_*6 + o6)*16 + l15;
      #pragma unroll
      for (int rr = 0; rr < 4; ++rr)
        stage[(l4*4 + rr)*C_ + c] = acc[o6][rr];
    }
    __syncthreads();
    for (int s2 = t; s2 < 768; s2 += 256) {
      int cc = s2 >> 6, lp = s2 & 63;
      int kp_l = lp & 15, l4g = lp >> 4;
      int c0 = cc*32 + l4g*8;
      u16 hh[8], ll[8];
      #pragma unroll
      for (int e = 0; e < 8; ++e) split_hl(stage[kp_l*C_ + c0 + e], hh[e], ll[e]);
      size_t fo = ((size_t)kb*12 + cc)*512 + (size_t)lp*8;
      *(ushort4*)&khi[fo]   = make_ushort4(hh[0],hh[1],hh[2],hh[3]);
      *(ushort4*)&khi[fo+4] = make_ushort4(hh[4],hh[5],hh[6],hh[7]);
      *(ushort4*)&klo[fo]   = make_ushort4(ll[0],ll[1],ll[2],ll[3]);
      *(ushort4*)&klo[fo+4] = make_ushort4(ll[4],ll[5],ll[6],ll[7]);
    }
    // V = X @ Wv, single-precision bf16
    f4v vac[6];
    #pragma unroll
    for (int i = 0; i < 6; ++i) vac[i] = (f4v){0.f,0.f,0.f,0.f};
    #pragma unroll 2
    for (int cs = 0; cs < 12; ++cs) {
      s8v ah = *(const s8v*)&fr[12288 + cs*512 + lane*8];
      #pragma unroll
      for (int o6 = 0; o6 < 6; ++o6) {
        int ot = wv_*6 + o6;
        s8v bh = *(const s8v*)&wvhi[((size_t)ot*12 + cs)*512 + lane*8];
        vac[o6] = MFMA(ah, bh, vac[o6]);
      }
    }
    __syncthreads();
    #pragma unroll
    for (int o6 = 0; o6 < 6; ++o6) {
      int c = (wv_*6 + o6)*16 + l15;
      #pragma unroll
      for (int rr = 0; rr < 4; ++rr)
        stage[(l4*4 + rr)*C_ + c] = vac[o6][rr];
    }
    __syncthreads();
    {
      int b = kb >> 5;
      int ks = (kb & 31) >> 1;
      int lg0 = (kb & 1) * 2;
      for (int s2 = t; s2 < 768; s2 += 256) {
        int c = s2 >> 1, half = s2 & 1;
        int lp = (c & 15) + 16*(lg0 + half);
        u16 hh[8];
        #pragma unroll
        for (int e = 0; e < 8; ++e)
          hh[e] = f2b_rne(stage[(half*8 + e)*C_ + c]);
        size_t fo = (((size_t)b*24 + (c >> 4))*16 + ks)*512 + (size_t)lp*8;
        *(ushort4*)&vthi[fo]   = make_ushort4(hh[0],hh[1],hh[2],hh[3]);
        *(ushort4*)&vthi[fo+4] = make_ushort4(hh[4],hh[5],hh[6],hh[7]);
      }
    }
  } else {
    // ======== qproj 32-row body ========
    int qb = blockIdx.x - 128;
    int row0 = qb * 32;
    #pragma unroll 1
    for (int tile = 0; tile < 2; ++tile) {
      int r = t >> 4, l = t & 15;
      const float* xr = st + (size_t)(row0 + tile*16 + r) * C_;
      float xv[24]; float s = 0.f;
      #pragma unroll
      for (int j = 0; j < 24; ++j) { xv[j] = xr[l + 16*j]; s += xv[j]; }
      #pragma unroll
      for (int m = 1; m < 16; m <<= 1) s += __shfl_xor(s, m);
      float mean = s * (1.0f/C_);
      float vs = 0.f;
      #pragma unroll
      for (int j = 0; j < 24; ++j) { float d = xv[j]-mean; vs += d*d; }
      #pragma unroll
      for (int m = 1; m < 16; m <<= 1) vs += __shfl_xor(vs, m);
      float rs = 1.0f / sqrtf(vs * (1.0f/C_) + 1e-5f);
      #pragma unroll
      for (int j = 0; j < 24; ++j) {
        int c = l + 16*j;
        float xc = (xv[j]-mean)*rs*gq[c] + bq[c];
        int idx = (c >> 5)*512 + ((r & 15) + 16*((c >> 3) & 3))*8 + (c & 7);
        u16 h, lo_;
        split_hl(xc, h, lo_);
        fr[tile*12288 + idx] = h; fr[tile*12288 + 6144 + idx] = lo_;
      }
    }
    __syncthreads();
    int wv_ = t >> 6, lane = t & 63;
    int l15 = lane & 15, l4 = lane >> 4;
    f4v acc0[6], acc1[6];
    #pragma unroll
    for (int i = 0; i < 6; ++i) {
      acc0[i] = (f4v){0.f,0.f,0.f,0.f};
      acc1[i] = (f4v){0.f,0.f,0.f,0.f};
    }
    #pragma unroll 2
    for (int cs = 0; cs < 12; ++cs) {
      s8v ah0 = *(const s8v*)&fr[cs*512 + lane*8];
      s8v al0 = *(const s8v*)&fr[6144 + cs*512 + lane*8];
      s8v ah1 = *(const s8v*)&fr[12288 + cs*512 + lane*8];
      s8v al1 = *(const s8v*)&fr[18432 + cs*512 + lane*8];
      #pragma unroll
      for (int o6 = 0; o6 < 6; ++o6) {
        int ot = wv_*6 + o6;
        s8v bh = *(const s8v*)&wqhi[((size_t)ot*12 + cs)*512 + lane*8];
        s8v bl = *(const s8v*)&wqlo[((size_t)ot*12 + cs)*512 + lane*8];
        acc0[o6] = MFMA(ah0, bh, acc0[o6]);
        acc0[o6] = MFMA(al0, bh, acc0[o6]);
        acc0[o6] = MFMA(ah0, bl, acc0[o6]);
        acc1[o6] = MFMA(ah1, bh, acc1[o6]);
        acc1[o6] = MFMA(al1, bh, acc1[o6]);
        acc1[o6] = MFMA(ah1, bl, acc1[o6]);
      }
    }
    __syncthreads();
    #pragma unroll
    for (int o6 = 0; o6 < 6; ++o6) {
      int c = (wv_*6 + o6)*16 + l15;
      #pragma unroll
      for (int rr = 0; rr < 4; ++rr) {
        stage[(l4*4 + rr)*C_ + c] = acc0[o6][rr];
        stage[(16 + l4*4 + rr)*C_ + c] = acc1[o6][rr];
      }
    }
    __syncthreads();
    #pragma unroll 1
    for (int tile = 0; tile < 2; ++tile) {
      for (int s2 = t; s2 < 768; s2 += 256) {
        int cc = s2 >> 6, lp = s2 & 63;
        int n_l = lp & 15, l4g = lp >> 4;
        int c0 = cc*32 + l4g*8;
        u16 hh[8], ll[8];
        #pragma unroll
        for (int e = 0; e < 8; ++e)
          split_hl(stage[(tile*16 + n_l)*C_ + c0 + e], hh[e], ll[e]);
        size_t fo = ((size_t)(qb*2 + tile)*12 + cc)*512 + (size_t)lp*8;
        *(ushort4*)&qhi[fo] = make_ushort4(hh[0],hh[1],hh[2],hh[3]);
        *(ushort4*)&qhi[fo+4] = make_ushort4(hh[4],hh[5],hh[6],hh[7]);
        *(ushort4*)&qlo[fo] = make_ushort4(ll[0],ll[1],ll[2],ll[3]);
        *(ushort4*)&qlo[fo+4] = make_ushort4(ll[4],ll[5],ll[6],ll[7]);
      }
    }
  }
}

// ---------------- K3: MFMA router: 32-n tile, 4 waves = 4 kp-quarters x 2 n-tiles ----------------
__global__ __launch_bounds__(256, 2) void k_route(
    const u16* __restrict__ qhi, const u16* __restrict__ qlo,
    const u16* __restrict__ khi, const u16* __restrict__ klo,
    const u16* __restrict__ vthi,
    const u16* __restrict__ spt,
    const u16* __restrict__ mshi,
    const float* __restrict__ mask_parent, const float* __restrict__ node_mask,
    float* __restrict__ out, u16* __restrict__ pf,
    float* __restrict__ mu0, float* __restrict__ sigpc) {
  __shared__ u16   wlds[32*512];        // 32 KB, XOR-swizzled rows
  __shared__ float smask[KP];           // 2 KB
  __shared__ float red[4][2][2][16];    // 1 KB
  __shared__ float musred[4][2][64][4]; // 8 KB

  int t = threadIdx.x;
  int blk = blockIdx.x;                  // 0..511
  int swz = (blk & 7) * 64 + (blk >> 3); // XCD-aware
  int bb = swz >> 7;
  int nb = (swz & 127) * 32;
  int wh = t >> 6, lane = t & 63;
  int l15 = lane & 15, l4 = lane >> 4;

  {
    const float4* ms = (const float4*)(mask_parent + (size_t)bb*KP);
    for (int i = t; i < 128; i += 256) ((float4*)smask)[i] = ms[i];
  }
  __syncthreads();

  const u16* qhB0 = qhi + ((size_t)(bb*256 + (nb >> 4)))*12*512;
  const u16* qlB0 = qlo + ((size_t)(bb*256 + (nb >> 4)))*12*512;
  const u16* qhB1 = qhB0 + 12*512;
  const u16* qlB1 = qlB0 + 12*512;
  const u16* khB = khi + ((size_t)(bb*32 + wh*8))*12*512;
  const u16* klB = klo + ((size_t)(bb*32 + wh*8))*12*512;
  f4v acc0[8], acc1[8];
  #pragma unroll
  for (int kt = 0; kt < 8; ++kt) {
    acc0[kt] = (f4v){0.f,0.f,0.f,0.f};
    acc1[kt] = (f4v){0.f,0.f,0.f,0.f};
  }
  #pragma unroll 4
  for (int cs = 0; cs < 12; ++cs) {
    s8v bqh0 = *(const s8v*)&qhB0[(size_t)cs*512 + lane*8];
    s8v bql0 = *(const s8v*)&qlB0[(size_t)cs*512 + lane*8];
    s8v bqh1 = *(const s8v*)&qhB1[(size_t)cs*512 + lane*8];
    s8v bql1 = *(const s8v*)&qlB1[(size_t)cs*512 + lane*8];
    #pragma unroll
    for (int kt = 0; kt < 8; ++kt) {
      s8v ah = *(const s8v*)&khB[((size_t)kt*12 + cs)*512 + lane*8];
      s8v al = *(const s8v*)&klB[((size_t)kt*12 + cs)*512 + lane*8];
      acc0[kt] = MFMA(ah, bqh0, acc0[kt]);
      acc0[kt] = MFMA(ah, bql0, acc0[kt]);
      acc0[kt] = MFMA(al, bqh0, acc0[kt]);
      acc1[kt] = MFMA(ah, bqh1, acc1[kt]);
      acc1[kt] = MFMA(ah, bql1, acc1[kt]);
      acc1[kt] = MFMA(al, bqh1, acc1[kt]);
    }
  }

  float mx0 = -3.4e38f, mx1 = -3.4e38f;
  #pragma unroll
  for (int kt = 0; kt < 8; ++kt) {
    const float4 m4 = *(const float4*)&smask[wh*128 + kt*16 + l4*4];
    acc0[kt][0] = (m4.x > 0.5f) ? acc0[kt][0]*TAU_INV : NEGV;
    acc0[kt][1] = (m4.y > 0.5f) ? acc0[kt][1]*TAU_INV : NEGV;
    acc0[kt][2] = (m4.z > 0.5f) ? acc0[kt][2]*TAU_INV : NEGV;
    acc0[kt][3] = (m4.w > 0.5f) ? acc0[kt][3]*TAU_INV : NEGV;
    acc1[kt][0] = (m4.x > 0.5f) ? acc1[kt][0]*TAU_INV : NEGV;
    acc1[kt][1] = (m4.y > 0.5f) ? acc1[kt][1]*TAU_INV : NEGV;
    acc1[kt][2] = (m4.z > 0.5f) ? acc1[kt][2]*TAU_INV : NEGV;
    acc1[kt][3] = (m4.w > 0.5f) ? acc1[kt][3]*TAU_INV : NEGV;
    mx0 = fmaxf(mx0, fmaxf(fmaxf(acc0[kt][0], acc0[kt][1]), fmaxf(acc0[kt][2], acc0[kt][3])));
    mx1 = fmaxf(mx1, fmaxf(fmaxf(acc1[kt][0], acc1[kt][1]), fmaxf(acc1[kt][2], acc1[kt][3])));
  }
  mx0 = fmaxf(mx0, __shfl_xor(mx0, 16));
  mx0 = fmaxf(mx0, __shfl_xor(mx0, 32));
  mx1 = fmaxf(mx1, __shfl_xor(mx1, 16));
  mx1 = fmaxf(mx1, __shfl_xor(mx1, 32));
  if (lane < 16) { red[wh][0][0][lane] = mx0; red[wh][1][0][lane] = mx1; }
  __syncthreads();
  mx0 = fmaxf(fmaxf(red[0][0][0][l15], red[1][0][0][l15]),
              fmaxf(red[2][0][0][l15], red[3][0][0][l15]));
  mx1 = fmaxf(fmaxf(red[0][1][0][l15], red[1][1][0][l15]),
              fmaxf(red[2][1][0][l15], red[3][1][0][l15]));
  float sm0 = 0.f, sm1 = 0.f;
  #pragma unroll
  for (int kt = 0; kt < 8; ++kt) {
    #pragma unroll
    for (int r = 0; r < 4; ++r) {
      float e0 = __expf(acc0[kt][r] - mx0);
      float e1 = __expf(acc1[kt][r] - mx1);
      acc0[kt][r] = e0; sm0 += e0;
      acc1[kt][r] = e1; sm1 += e1;
    }
  }
  sm0 += __shfl_xor(sm0, 16); sm0 += __shfl_xor(sm0, 32);
  sm1 += __shfl_xor(sm1, 16); sm1 += __shfl_xor(sm1, 32);
  if (lane < 16) { red[wh][0][1][lane] = sm0; red[wh][1][1][lane] = sm1; }
  __syncthreads();
  sm0 = red[0][0][1][l15] + red[1][0][1][l15] + red[2][0][1][l15] + red[3][0][1][l15];
  sm1 = red[0][1][1][l15] + red[1][1][1][l15] + red[2][1][1][l15] + red[3][1][1][l15];
  float nm0 = node_mask[(size_t)bb*N_ + nb + l15];
  float nm1 = node_mask[(size_t)bb*N_ + nb + 16 + l15];
  float scl0 = nm0 / sm0, scl1 = nm1 / sm1;
  bool uni0 = !(nm0 > 0.5f), uni1 = !(nm1 > 0.5f);
  float uv0 = nm0 * (1.0f/KP), uv1 = nm1 * (1.0f/KP);
  #pragma unroll
  for (int kt = 0; kt < 8; ++kt) {
    int kpl = wh*128 + kt*16 + l4*4;
    ushort4 wv0, wv1;
    wv0.x = f2b_rne(uni0 ? uv0 : acc0[kt][0]*scl0);
    wv0.y = f2b_rne(uni0 ? uv0 : acc0[kt][1]*scl0);
    wv0.z = f2b_rne(uni0 ? uv0 : acc0[kt][2]*scl0);
    wv0.w = f2b_rne(uni0 ? uv0 : acc0[kt][3]*scl0);
    wv1.x = f2b_rne(uni1 ? uv1 : acc1[kt][0]*scl1);
    wv1.y = f2b_rne(uni1 ? uv1 : acc1[kt][1]*scl1);
    wv1.z = f2b_rne(uni1 ? uv1 : acc1[kt][2]*scl1);
    wv1.w = f2b_rne(uni1 ? uv1 : acc1[kt][3]*scl1);
    int bo0 = (l15*1024 + kpl*2) ^ ((l15 & 7) << 4);
    int bo1 = ((l15+16)*1024 + kpl*2) ^ ((l15 & 7) << 4);
    *(ushort4*)&wlds[bo0 >> 1] = wv0;
    *(ushort4*)&wlds[bo1 >> 1] = wv1;
  }
  __syncthreads();

  #pragma unroll 2
  for (int ct = 0; ct < 6; ++ct) {
    int c_tile = wh*6 + ct;
    int c = c_tile*16 + l15;
    f4v aS0 = (f4v){0.f,0.f,0.f,0.f}, aS1 = aS0;
    f4v aP0 = aS0, aP1 = aS0;
    const u16* vhB = vthi + (((size_t)bb*24 + c_tile)*16)*512;
    const u16* spB = spt  + (((size_t)bb*24 + c_tile)*16)*512;
    #pragma unroll
    for (int ks = 0; ks < 16; ++ks) {
      int kp = ks*32 + l4*8;
      int bo0 = (l15*1024 + kp*2) ^ ((l15 & 7) << 4);
      int bo1 = ((l15+16)*1024 + kp*2) ^ ((l15 & 7) << 4);
      s8v aw0 = *(const s8v*)&wlds[bo0 >> 1];
      s8v aw1 = *(const s8v*)&wlds[bo1 >> 1];
      s8v bh = *(const s8v*)&vhB[(size_t)ks*512 + lane*8];
      s8v bs = *(const s8v*)&spB[(size_t)ks*512 + lane*8];
      aS0 = MFMA(aw0, bh, aS0);
      aP0 = MFMA(aw0, bs, aP0);
      aS1 = MFMA(aw1, bh, aS1);
      aP1 = MFMA(aw1, bs, aP1);
    }
    #pragma unroll
    for (int r = 0; r < 4; ++r) {
      int n0r = nb + l4*4 + r;
      int n1r = n0r + 16;
      size_t row0_ = (size_t)bb*N_ + n0r;
      size_t row1_ = (size_t)bb*N_ + n1r;
      out[row0_*396 + c] = aS0[r];
      out[row1_*396 + c] = aS1[r];
      pf[row0_*C_ + c] = f2b_rne(aP0[r]);
      pf[row1_*C_ + c] = f2b_rne(aP1[r]);
    }
  }

  // tail: single-precision musig
  {
    f4v p0 = (f4v){0.f,0.f,0.f,0.f}, p1 = p0;
    #pragma unroll
    for (int k2 = 0; k2 < 4; ++k2) {
      int ks = wh*4 + k2;
      int kp = ks*32 + l4*8;
      int bo0 = (l15*1024 + kp*2) ^ ((l15 & 7) << 4);
      int bo1 = ((l15+16)*1024 + kp*2) ^ ((l15 & 7) << 4);
      s8v aw0 = *(const s8v*)&wlds[bo0 >> 1];
      s8v aw1 = *(const s8v*)&wlds[bo1 >> 1];
      s8v bh = *(const s8v*)&mshi[(((size_t)bb*16 + ks)*64 + lane)*8];
      p0 = MFMA(aw0, bh, p0);
      p1 = MFMA(aw1, bh, p1);
    }
    #pragma unroll
    for (int r = 0; r < 4; ++r) {
      musred[wh][0][lane][r] = p0[r];
      musred[wh][1][lane][r] = p1[r];
    }
  }
  __syncthreads();
  if (wh < 2) {
    int tile = wh;
    int col = l15;
    #pragma unroll
    for (int r = 0; r < 4; ++r) {
      float d = musred[0][tile][lane][r] + musred[1][tile][lane][r]
              + musred[2][tile][lane][r] + musred[3][tile][lane][r];
      int n = nb + tile*16 + l4*4 + r;
      size_t row = (size_t)bb*N_ + n;
      if (col < 3) {
        mu0[row*3 + col] = d;
      } else if (col < 12) {
        int e = col - 3;
        if (e == 0 || e == 4 || e == 8) d += JITTER_;
        sigpc[row*9 + e] = d;
      }
    }
  }
}

// ---------------- K4: mu-offset MLP (MFMA, 32 rows/block, single-precision h) ----------------
__global__ __launch_bounds__(256) void k_mlp(
    const u16* __restrict__ pf, const float* __restrict__ g,
    const float* __restrict__ bb,
    const u16* __restrict__ w1hi,
    const float* __restrict__ b1, const float* __restrict__ W2,
    const float* __restrict__ b2v, const float* __restrict__ node_mask,
    float* __restrict__ mu0) {
  __shared__ u16 fr[4*6144];
  float* stage = (float*)fr;
  int t = threadIdx.x;
  int row0 = blockIdx.x * 32;
  #pragma unroll 1
  for (int tile = 0; tile < 2; ++tile) {
    int r = t >> 4, l = t & 15;
    const u16* xr = pf + (size_t)(row0 + tile*16 + r) * C_;
    float xv[24]; float s = 0.f;
    #pragma unroll
    for (int j = 0; j < 24; ++j) { xv[j] = b2f(xr[l + 16*j]); s += xv[j]; }
    #pragma unroll
    for (int m = 1; m < 16; m <<= 1) s += __shfl_xor(s, m);
    float mean = s * (1.0f/C_);
    float vs = 0.f;
    #pragma unroll
    for (int j = 0; j < 24; ++j) { float d = xv[j]-mean; vs += d*d; }
    #pragma unroll
    for (int m = 1; m < 16; m <<= 1) vs += __shfl_xor(vs, m);
    float rs = 1.0f / sqrtf(vs * (1.0f/C_) + 1e-5f);
    #pragma unroll
    for (int j = 0; j < 24; ++j) {
      int c = l + 16*j;
      float xc = (xv[j]-mean)*rs*g[c] + bb[c];
      int idx = (c >> 5)*512 + ((r & 15) + 16*((c >> 3) & 3))*8 + (c & 7);
      fr[tile*12288 + idx] = f2b_rne(xc);
    }
  }
  __syncthreads();
  int wv_ = t >> 6, lane = t & 63;
  int l15 = lane & 15, l4 = lane >> 4;
  f4v acc0[6], acc1[6];
  #pragma unroll
  for (int i = 0; i < 6; ++i) {
    acc0[i] = (f4v){0.f,0.f,0.f,0.f};
    acc1[i] = (f4v){0.f,0.f,0.f,0.f};
  }
  #pragma unroll 2
  for (int cs = 0; cs < 12; ++cs) {
    s8v ah0 = *(const s8v*)&fr[cs*512 + lane*8];
    s8v ah1 = *(const s8v*)&fr[12288 + cs*512 + lane*8];
    #pragma unroll
    for (int o6 = 0; o6 < 6; ++o6) {
      int ot = wv_*6 + o6;
      s8v bh = *(const s8v*)&w1hi[((size_t)ot*12 + cs)*512 + lane*8];
      acc0[o6] = MFMA(ah0, bh, acc0[o6]);
      acc1[o6] = MFMA(ah1, bh, acc1[o6]);
    }
  }
  __syncthreads();
  #pragma unroll
  for (int o6 = 0; o6 < 6; ++o6) {
    int c = (wv_*6 + o6)*16 + l15;
    float bv = b1[c];
    #pragma unroll
    for (int rr = 0; rr < 4; ++rr) {
      float v0 = acc0[o6][rr] + bv;
      stage[(l4*4 + rr)*C_ + c] = v0 / (1.0f + __expf(-v0));
      float v1 = acc1[o6][rr] + bv;
      stage[(16 + l4*4 + rr)*C_ + c] = v1 / (1.0f + __expf(-v1));
    }
  }
  __syncthreads();
  #pragma unroll 1
  for (int tile = 0; tile < 2; ++tile) {
    int r = t >> 4, l = t & 15;
    const float* hr = &stage[(tile*16 + r)*C_];
    float pd0=0.f, pd1=0.f, pd2=0.f;
    #pragma unroll
    for (int j=0;j<24;++j) {
      int c = l + 16*j;
      float hv = hr[c];
      pd0 += hv*W2[c];
      pd1 += hv*W2[C_ + c];
      pd2 += hv*W2[2*C_ + c];
    }
    #pragma unroll
    for (int m = 1; m < 16; m <<= 1) {
      pd0 += __shfl_xor(pd0, m);
      pd1 += __shfl_xor(pd1, m);
      pd2 += __shfl_xor(pd2, m);
    }
    if (l == 0) {
      size_t row = (size_t)(row0 + tile*16 + r);
      float nmv = node_mask[row];
      float d0 = (pd0 + b2v[0]) * MU_SCALE_;
      float d1 = (pd1 + b2v[1]) * MU_SCALE_;
      float d2 = (pd2 + b2v[2]) * MU_SCALE_;
      mu0[row*3+0] = (mu0[row*3+0] + d0) * nmv;
      mu0[row*3+1] = (mu0[row*3+1] + d1) * nmv;
      mu0[row*3+2] = (mu0[row*3+2] + d2) * nmv;
    }
  }
}

// ---------------- K5: kNN sigma + Sig0 + mu0 out ----------------
__global__ __launch_bounds__(512, 4) void k_knn(
    const float* __restrict__ mu0, const float* __restrict__ node_mask,
    const float* __restrict__ sigpc, float* __restrict__ out) {
  __shared__ float4 cand[N_];
  int t = threadIdx.x;
  int b = blockIdx.y;
  int n0 = blockIdx.x * 32;
  const float* mb = mu0 + (size_t)b*N_*3;
  const float* nmB = node_mask + (size_t)b*N_;
  for (int idx = t; idx < N_; idx += 512) {
    float x = mb[idx*3+0], y = mb[idx*3+1], z = mb[idx*3+2];
    float w = (nmB[idx] > 0.5f) ? 0.f : BIG_;
    cand[idx] = make_float4(x, y, z, w);
  }
  __syncthreads();
  int r = t >> 4, qq = t & 15;
  int n = n0 + r;
  float4 e = cand[n];
  float best[8];
  #pragma unroll
  for (int i=0;i<8;++i) best[i] = BIG_;
  int base = qq * 256;
  #pragma unroll 4
  for (int i = 0; i < 256; ++i) {
    int m = base + ((i + qq) & 255);
    float4 c = cand[m];
    float dx = c.x - e.x, dy = c.y - e.y, dz = c.z - e.z;
    float d2 = dx*dx + dy*dy + dz*dz + c.w;
    if (m == n) d2 = BIG_;
    if (d2 < best[7]) {
      #pragma unroll
      for (int i2 = 7; i2 >= 1; --i2)
        best[i2] = (best[i2] > d2) ? ((best[i2-1] > d2) ? best[i2-1] : d2) : best[i2];
      best[0] = (best[0] > d2) ? d2 : best[0];
    }
  }
  #pragma unroll
  for (int mk = 1; mk <= 8; mk <<= 1) {
    float ob[8];
    #pragma unroll
    for (int i = 0; i < 8; ++i) ob[i] = __shfl_xor(best[7-i], mk);
    #pragma unroll
    for (int i = 0; i < 8; ++i) best[i] = fminf(best[i], ob[i]);
    #pragma unroll
    for (int i = 0; i < 4; ++i) {
      float lo = fminf(best[i], best[i+4]);
      float hi = fmaxf(best[i], best[i+4]);
      best[i] = lo; best[i+4] = hi;
    }
    #pragma unroll
    for (int gI = 0; gI < 2; ++gI) {
      int o = gI*4;
      float lo0 = fminf(best[o+0], best[o+2]);
      float hi0 = fmaxf(best[o+0], best[o+2]);
      float lo1 = fminf(best[o+1], best[o+3]);
      float hi1 = fmaxf(best[o+1], best[o+3]);
      best[o+0]=lo0; best[o+2]=hi0; best[o+1]=lo1; best[o+3]=hi1;
    }
    #pragma unroll
    for (int p = 0; p < 8; p += 2) {
      float lo = fminf(best[p], best[p+1]);
      float hi = fmaxf(best[p], best[p+1]);
      best[p] = lo; best[p+1] = hi;
    }
  }
  if (qq == 0) {
    float ssum = 0.f;
    #pragma unroll
    for (int i = 0; i < 8; ++i) ssum += sqrtf(fmaxf(best[i], 0.f));
    float sigma = fminf(fmaxf(ALPHA_ * (ssum * 0.125f), SFLOOR_), SCEIL_);
    float s2 = sigma*sigma + JITTER_;
    size_t row = (size_t)b*N_ + n;
    float nmv = nmB[n];
    size_t orow = row * 396;
    const float* sg = &sigpc[row*9];
    #pragma unroll
    for (int e2=0;e2<9;++e2) {
      bool diag = (e2==0)||(e2==4)||(e2==8);
      float v = BETA_*sg[e2] + (diag ? ((1.0f-BETA_)*s2 + JITTER_) : 0.0f);
      out[orow + 387 + e2] = v * nmv;
    }
    out[orow + 384] = e.x;
    out[orow + 385] = e.y;
    out[orow + 386] = e.z;
  }
}

extern "C" void kernel_launch(void* const* d_in, const int* in_sizes, int n_in,
                              void* d_out, int out_size, void* d_ws, size_t ws_size,
                              hipStream_t stream) {
  const float* s_parent    = (const float*)d_in[0];
  const float* mu_p        = (const float*)d_in[1];
  const float* Sig_p       = (const float*)d_in[2];
  const float* mask_parent = (const float*)d_in[3];
  const float* node_mask   = (const float*)d_in[4];
  const float* s_trunk     = (const float*)d_in[5];
  const float* Wq   = (const float*)d_in[6];
  const float* Wk   = (const float*)d_in[7];
  const float* Wv   = (const float*)d_in[8];
  const float* Wpos = (const float*)d_in[9];
  const float* lnq_g = (const float*)d_in[10];
  const float* lnq_b = (const float*)d_in[11];
  const float* lnk_g = (const float*)d_in[12];
  const float* lnk_b = (const float*)d_in[13];
  const float* lnv_g = (const float*)d_in[14];
  const float* lnv_b = (const float*)d_in[15];
  const float* mo_ln_g = (const float*)d_in[16];
  const float* mo_ln_b = (const float*)d_in[17];
  const float* mo_W1 = (const float*)d_in[18];
  const float* mo_b1 = (const float*)d_in[19];
  const float* mo_W2 = (const float*)d_in[20];
  const float* mo_b2 = (const float*)d_in[21];

  char* wsb = (char*)d_ws;
  u16* qhi  = (u16*)wsb;
  u16* qlo  = qhi + (size_t)B_*N_*C_;
  u16* khi  = (u16*)(wsb + 25165824);
  u16* klo  = khi + (size_t)B_*KP*C_;
  u16* vthi = (u16*)(wsb + 25165824 + 3145728);
  char* pfb = wsb + 25165824 + 2*3145728;
  u16* pf   = (u16*)pfb;
  u16* spt  = (u16*)(pfb + 12582912);
  char* pw  = pfb + 12582912 + 1572864;
  u16* wqhi  = (u16*)pw;                         // 294912 B each
  u16* wqlo  = (u16*)(pw + 294912);
  u16* wkhi  = (u16*)(pw + 589824);
  u16* wklo  = (u16*)(pw + 884736);
  u16* wvhi  = (u16*)(pw + 1179648);
  u16* mshi  = (u16*)(pw + 1769472);             // 65536 B
  u16* w1hi  = (u16*)(pw + 1900544);             // 294912 B
  float* mu0 = (float*)(wsb + 25165824 + 2*3145728 + 25165824);
  float* sg  = mu0 + (size_t)B_*N_*3;
  float* out = (float*)d_out;

  k_prep<<<dim3(868), dim3(256), 0, stream>>>(
      Wq, Wk, Wv, mo_W1, s_parent, mu_p, Sig_p,
      wqhi, wqlo, wkhi, wklo, wvhi, w1hi,
      spt, mshi);
  k_kq<<<dim3(640), dim3(256), 0, stream>>>(
      s_parent, mu_p, lnk_g, lnk_b, lnv_g, lnv_b,
      wkhi, wklo, wvhi, Wpos,
      khi, klo, vthi,
      s_trunk, lnq_g, lnq_b, wqhi, wqlo, qhi, qlo);
  k_route<<<dim3(512), dim3(256), 0, stream>>>(
      qhi, qlo, khi, klo, vthi, spt, mshi,
      mask_parent, node_mask, out, pf, mu0, sg);
  k_mlp<<<dim3(B_*N_/32), dim3(256), 0, stream>>>(
      pf, mo_ln_g, mo_ln_b, w1hi, mo_b1, mo_W2, mo_b2, node_mask, mu0);
  k_knn<<<dim3(N_/32, B_), dim3(512), 0, stream>>>(
      mu0, node_mask, sg, out);
}

// Round 22
// 200.837 us; speedup vs baseline: 1.1253x; 1.1253x over previous
//
#include <hip/hip_runtime.h>
#include <math.h>

#define B_ 4
#define N_ 4096
#define KP 512
#define C_ 384

typedef unsigned short u16;
typedef short s8v __attribute__((ext_vector_type(8)));
typedef float f4v __attribute__((ext_vector_type(4)));
#define MFMA(a,b,c) __builtin_amdgcn_mfma_f32_16x16x32_bf16(a,b,c,0,0,0)

constexpr float TAU_INV  = 10.0f;
constexpr float BETA_    = 0.85f;
constexpr float JITTER_  = 1e-6f;
constexpr float ALPHA_   = 1.5f;
constexpr float SFLOOR_  = 1e-3f;
constexpr float SCEIL_   = 100.0f;
constexpr float MU_SCALE_= 0.25f;
constexpr float NEGV     = -1e9f;
constexpr float BIG_     = 1e9f;

__device__ __forceinline__ u16 f2b_rne(float f) {
  unsigned int u = __float_as_uint(f);
  return (u16)((u + 0x7FFFu + ((u >> 16) & 1u)) >> 16);
}
__device__ __forceinline__ float b2f(u16 h) {
  return __uint_as_float(((unsigned int)h) << 16);
}
__device__ __forceinline__ void split_hl(float f, u16& hi, u16& lo) {
  unsigned int u = __float_as_uint(f);
  hi = (u16)(u >> 16);
  float fh = __uint_as_float(u & 0xFFFF0000u);
  lo = f2b_rne(f - fh);
}

// Packed fragment layouts (per 16x16x32 MFMA), 1KB contiguous per fragment:
//  K (A-op):   [b*32+kp_tile][cc(12)][lane][8], lane=(kp&15)+16*((c>>3)&3)
//  q (B-op):   [n>>4][cc(12)][lane][8],        lane=(n&15)+16*((c>>3)&3)
//  V^T/spT (B-op): [b*24+c_tile][ks(16)][lane][8], lane=(c&15)+16*((kp>>3)&3)
//  W (B-op):   [ot(24)][cs(12)][lane][8],      lane=(outc&15)+16*((inc>>3)&3)
//  musig (B-op): [b][ks(16)][lane][8], cols 0-2=mu, 3-11=symSig, 12-15=0

// ---------------- device helper: pack one W ot-tile ----------------
__device__ __forceinline__ void wpack_body(
    const float* __restrict__ W, u16* __restrict__ whi, u16* __restrict__ wlo,
    int ot, int t) {
  for (int s = t; s < 768; s += 256) {
    int cs = s >> 6, lane = s & 63;
    int outc = ot*16 + (lane & 15);
    int inc0 = cs*32 + (lane >> 4)*8;
    u16 hh[8], ll[8];
    #pragma unroll
    for (int e = 0; e < 8; ++e)
      split_hl(W[(size_t)outc*C_ + inc0 + e], hh[e], ll[e]);
    size_t fo = ((size_t)ot*12 + cs)*512 + (size_t)lane*8;
    *(ushort4*)&whi[fo]   = make_ushort4(hh[0],hh[1],hh[2],hh[3]);
    *(ushort4*)&whi[fo+4] = make_ushort4(hh[4],hh[5],hh[6],hh[7]);
    if (wlo) {
      *(ushort4*)&wlo[fo]   = make_ushort4(ll[0],ll[1],ll[2],ll[3]);
      *(ushort4*)&wlo[fo+4] = make_ushort4(ll[4],ll[5],ll[6],ll[7]);
    }
  }
}

// ---------------- K0: merged prep: wpack(Wq,Wk,Wv,W1) + sptr + musig ----------------
__global__ __launch_bounds__(256) void k_prep(
    const float* __restrict__ Wq, const float* __restrict__ Wk,
    const float* __restrict__ Wv, const float* __restrict__ W1,
    const float* __restrict__ sp, const float* __restrict__ mu_p,
    const float* __restrict__ Sig_p,
    u16* __restrict__ wqhi, u16* __restrict__ wqlo,
    u16* __restrict__ wkhi, u16* __restrict__ wklo,
    u16* __restrict__ wvhi,
    u16* __restrict__ w1hi,
    u16* __restrict__ spt,
    u16* __restrict__ mshi) {
  __shared__ float tl[32][33];
  int blk = blockIdx.x;
  int t = threadIdx.x;
  if (blk < 96) {
    int which = blk / 24, ot = blk % 24;
    if (which == 0)      wpack_body(Wq, wqhi, wqlo, ot, t);
    else if (which == 1) wpack_body(Wk, wkhi, wklo, ot, t);
    else if (which == 2) wpack_body(Wv, wvhi, (u16*)0, ot, t);
    else                 wpack_body(W1, w1hi, (u16*)0, ot, t);
  } else if (blk < 864) {
    int u = blk - 96;
    int bz = u / 192, rem = u % 192;
    int by = (rem / 16) * 32;   // c
    int bx = (rem % 16) * 32;   // kp
    const float* s = sp + (size_t)bz * KP * C_;
    int tx = t & 31, ty4 = t >> 5;
    #pragma unroll
    for (int j = 0; j < 32; j += 8)
      tl[ty4 + j][tx] = s[(size_t)(bx + ty4 + j) * C_ + by + tx];
    __syncthreads();
    if (t < 128) {
      int c_l = t >> 2, krun = t & 3;
      int kp0r = krun * 8;
      u16 hh[8];
      #pragma unroll
      for (int e = 0; e < 8; ++e) hh[e] = f2b_rne(tl[kp0r + e][c_l]);
      int cg = by + c_l;
      int lane = (cg & 15) + 16 * krun;
      size_t fo = (((size_t)bz*24 + (cg >> 4))*16 + (bx >> 5))*512 + (size_t)lane*8;
      *(ushort4*)&spt[fo]   = make_ushort4(hh[0],hh[1],hh[2],hh[3]);
      *(ushort4*)&spt[fo+4] = make_ushort4(hh[4],hh[5],hh[6],hh[7]);
    }
  } else {
    int b = blk - 864;
    for (int s = t; s < 1024; s += 256) {
      int ks = s >> 6, lane = s & 63;
      int col = lane & 15, kb = lane >> 4;
      u16 hh[8];
      #pragma unroll
      for (int e = 0; e < 8; ++e) {
        int kp = ks*32 + kb*8 + e;
        float v = 0.f;
        if (col < 3) {
          v = mu_p[((size_t)b*KP + kp)*3 + col];
        } else if (col < 12) {
          int ee = col - 3, ii = ee/3, jj = ee%3;
          const float* sg = &Sig_p[((size_t)b*KP + kp)*9];
          v = 0.5f*(sg[ii*3+jj] + sg[jj*3+ii]);
        }
        hh[e] = f2b_rne(v);
      }
      size_t fo = (((size_t)b*16 + ks)*64 + lane)*8;
      *(ushort4*)&mshi[fo]   = make_ushort4(hh[0],hh[1],hh[2],hh[3]);
      *(ushort4*)&mshi[fo+4] = make_ushort4(hh[4],hh[5],hh[6],hh[7]);
    }
  }
}

// ---------------- K1: merged kvproj (blocks 0..127) + qproj 32-row (128..639) ----------------
__global__ __launch_bounds__(256) void k_kq(
    const float* __restrict__ sp, const float* __restrict__ mu_p,
    const float* __restrict__ gk, const float* __restrict__ bk,
    const float* __restrict__ gv, const float* __restrict__ bv,
    const u16* __restrict__ wkhi, const u16* __restrict__ wklo,
    const u16* __restrict__ wvhi,
    const float* __restrict__ Wpos,
    u16* __restrict__ khi, u16* __restrict__ klo,
    u16* __restrict__ vthi,
    const float* __restrict__ st, const float* __restrict__ gq,
    const float* __restrict__ bq,
    const u16* __restrict__ wqhi, const u16* __restrict__ wqlo,
    u16* __restrict__ qhi, u16* __restrict__ qlo) {
  __shared__ u16 fr[4*6144];
  float* stage = (float*)fr;
  int t = threadIdx.x;
  if (blockIdx.x < 128) {
    // ======== kvproj body ========
    int kb = blockIdx.x;
    int pr0 = kb * 16;
    {
      int r = t >> 4, l = t & 15;
      const float* xr = sp + (size_t)(pr0 + r) * C_;
      float xv[24]; float s = 0.f;
      #pragma unroll
      for (int j = 0; j < 24; ++j) { xv[j] = xr[l + 16*j]; s += xv[j]; }
      #pragma unroll
      for (int m = 1; m < 16; m <<= 1) s += __shfl_xor(s, m);
      float mean = s * (1.0f/C_);
      float vs = 0.f;
      #pragma unroll
      for (int j = 0; j < 24; ++j) { float d = xv[j]-mean; vs += d*d; }
      #pragma unroll
      for (int m = 1; m < 16; m <<= 1) vs += __shfl_xor(vs, m);
      float rs = 1.0f / sqrtf(vs * (1.0f/C_) + 1e-5f);
      #pragma unroll
      for (int j = 0; j < 24; ++j) {
        int c = l + 16*j;
        float xc = (xv[j]-mean)*rs;
        int idx = (c >> 5)*512 + ((r & 15) + 16*((c >> 3) & 3))*8 + (c & 7);
        u16 h, lo_;
        split_hl(xc*gk[c] + bk[c], h, lo_);
        fr[idx] = h; fr[6144 + idx] = lo_;
        fr[12288 + idx] = f2b_rne(xc*gv[c] + bv[c]);
      }
    }
    __syncthreads();
    int wv_ = t >> 6, lane = t & 63;
    int l15 = lane & 15, l4 = lane >> 4;
    float mur[4][3];
    #pragma unroll
    for (int rr = 0; rr < 4; ++rr) {
      int prow = pr0 + l4*4 + rr;
      mur[rr][0] = mu_p[(size_t)prow*3+0];
      mur[rr][1] = mu_p[(size_t)prow*3+1];
      mur[rr][2] = mu_p[(size_t)prow*3+2];
    }
    f4v acc[6];
    #pragma unroll
    for (int i = 0; i < 6; ++i) acc[i] = (f4v){0.f,0.f,0.f,0.f};
    for (int cs = 0; cs < 12; ++cs) {
      s8v ah = *(const s8v*)&fr[cs*512 + lane*8];
      s8v al = *(const s8v*)&fr[6144 + cs*512 + lane*8];
      #pragma unroll
      for (int o6 = 0; o6 < 6; ++o6) {
        int ot = wv_*6 + o6;
        s8v bh = *(const s8v*)&wkhi[((size_t)ot*12 + cs)*512 + lane*8];
        s8v bl = *(const s8v*)&wklo[((size_t)ot*12 + cs)*512 + lane*8];
        acc[o6] = MFMA(ah, bh, acc[o6]);
        acc[o6] = MFMA(al, bh, acc[o6]);
        acc[o6] = MFMA(ah, bl, acc[o6]);
      }
    }
    #pragma unroll
    for (int o6 = 0; o6 < 6; ++o6) {
      int outc = (wv_*6 + o6)*16 + l15;
      float w0 = Wpos[outc*3+0], w1 = Wpos[outc*3+1], w2 = Wpos[outc*3+2];
      #pragma unroll
      for (int rr = 0; rr < 4; ++rr)
        acc[o6][rr] += mur[rr][0]*w0 + mur[rr][1]*w1 + mur[rr][2]*w2;
    }
    __syncthreads();
    #pragma unroll
    for (int o6 = 0; o6 < 6; ++o6) {
      int c = (wv_*6 + o6)*16 + l15;
      #pragma unroll
      for (int rr = 0; rr < 4; ++rr)
        stage[(l4*4 + rr)*C_ + c] = acc[o6][rr];
    }
    __syncthreads();
    for (int s2 = t; s2 < 768; s2 += 256) {
      int cc = s2 >> 6, lp = s2 & 63;
      int kp_l = lp & 15, l4g = lp >> 4;
      int c0 = cc*32 + l4g*8;
      u16 hh[8], ll[8];
      #pragma unroll
      for (int e = 0; e < 8; ++e) split_hl(stage[kp_l*C_ + c0 + e], hh[e], ll[e]);
      size_t fo = ((size_t)kb*12 + cc)*512 + (size_t)lp*8;
      *(ushort4*)&khi[fo]   = make_ushort4(hh[0],hh[1],hh[2],hh[3]);
      *(ushort4*)&khi[fo+4] = make_ushort4(hh[4],hh[5],hh[6],hh[7]);
      *(ushort4*)&klo[fo]   = make_ushort4(ll[0],ll[1],ll[2],ll[3]);
      *(ushort4*)&klo[fo+4] = make_ushort4(ll[4],ll[5],ll[6],ll[7]);
    }
    // V = X @ Wv, single-precision bf16 (error ~0.004 abs, within budget)
    f4v vac[6];
    #pragma unroll
    for (int i = 0; i < 6; ++i) vac[i] = (f4v){0.f,0.f,0.f,0.f};
    for (int cs = 0; cs < 12; ++cs) {
      s8v ah = *(const s8v*)&fr[12288 + cs*512 + lane*8];
      #pragma unroll
      for (int o6 = 0; o6 < 6; ++o6) {
        int ot = wv_*6 + o6;
        s8v bh = *(const s8v*)&wvhi[((size_t)ot*12 + cs)*512 + lane*8];
        vac[o6] = MFMA(ah, bh, vac[o6]);
      }
    }
    __syncthreads();
    #pragma unroll
    for (int o6 = 0; o6 < 6; ++o6) {
      int c = (wv_*6 + o6)*16 + l15;
      #pragma unroll
      for (int rr = 0; rr < 4; ++rr)
        stage[(l4*4 + rr)*C_ + c] = vac[o6][rr];
    }
    __syncthreads();
    {
      int b = kb >> 5;
      int ks = (kb & 31) >> 1;
      int lg0 = (kb & 1) * 2;
      for (int s2 = t; s2 < 768; s2 += 256) {
        int c = s2 >> 1, half = s2 & 1;
        int lp = (c & 15) + 16*(lg0 + half);
        u16 hh[8];
        #pragma unroll
        for (int e = 0; e < 8; ++e)
          hh[e] = f2b_rne(stage[(half*8 + e)*C_ + c]);
        size_t fo = (((size_t)b*24 + (c >> 4))*16 + ks)*512 + (size_t)lp*8;
        *(ushort4*)&vthi[fo]   = make_ushort4(hh[0],hh[1],hh[2],hh[3]);
        *(ushort4*)&vthi[fo+4] = make_ushort4(hh[4],hh[5],hh[6],hh[7]);
      }
    }
  } else {
    // ======== qproj 32-row body ========
    int qb = blockIdx.x - 128;
    int row0 = qb * 32;
    #pragma unroll 1
    for (int tile = 0; tile < 2; ++tile) {
      int r = t >> 4, l = t & 15;
      const float* xr = st + (size_t)(row0 + tile*16 + r) * C_;
      float xv[24]; float s = 0.f;
      #pragma unroll
      for (int j = 0; j < 24; ++j) { xv[j] = xr[l + 16*j]; s += xv[j]; }
      #pragma unroll
      for (int m = 1; m < 16; m <<= 1) s += __shfl_xor(s, m);
      float mean = s * (1.0f/C_);
      float vs = 0.f;
      #pragma unroll
      for (int j = 0; j < 24; ++j) { float d = xv[j]-mean; vs += d*d; }
      #pragma unroll
      for (int m = 1; m < 16; m <<= 1) vs += __shfl_xor(vs, m);
      float rs = 1.0f / sqrtf(vs * (1.0f/C_) + 1e-5f);
      #pragma unroll
      for (int j = 0; j < 24; ++j) {
        int c = l + 16*j;
        float xc = (xv[j]-mean)*rs*gq[c] + bq[c];
        int idx = (c >> 5)*512 + ((r & 15) + 16*((c >> 3) & 3))*8 + (c & 7);
        u16 h, lo_;
        split_hl(xc, h, lo_);
        fr[tile*12288 + idx] = h; fr[tile*12288 + 6144 + idx] = lo_;
      }
    }
    __syncthreads();
    int wv_ = t >> 6, lane = t & 63;
    int l15 = lane & 15, l4 = lane >> 4;
    f4v acc0[6], acc1[6];
    #pragma unroll
    for (int i = 0; i < 6; ++i) {
      acc0[i] = (f4v){0.f,0.f,0.f,0.f};
      acc1[i] = (f4v){0.f,0.f,0.f,0.f};
    }
    for (int cs = 0; cs < 12; ++cs) {
      s8v ah0 = *(const s8v*)&fr[cs*512 + lane*8];
      s8v al0 = *(const s8v*)&fr[6144 + cs*512 + lane*8];
      s8v ah1 = *(const s8v*)&fr[12288 + cs*512 + lane*8];
      s8v al1 = *(const s8v*)&fr[18432 + cs*512 + lane*8];
      #pragma unroll
      for (int o6 = 0; o6 < 6; ++o6) {
        int ot = wv_*6 + o6;
        s8v bh = *(const s8v*)&wqhi[((size_t)ot*12 + cs)*512 + lane*8];
        s8v bl = *(const s8v*)&wqlo[((size_t)ot*12 + cs)*512 + lane*8];
        acc0[o6] = MFMA(ah0, bh, acc0[o6]);
        acc0[o6] = MFMA(al0, bh, acc0[o6]);
        acc0[o6] = MFMA(ah0, bl, acc0[o6]);
        acc1[o6] = MFMA(ah1, bh, acc1[o6]);
        acc1[o6] = MFMA(al1, bh, acc1[o6]);
        acc1[o6] = MFMA(ah1, bl, acc1[o6]);
      }
    }
    __syncthreads();
    #pragma unroll
    for (int o6 = 0; o6 < 6; ++o6) {
      int c = (wv_*6 + o6)*16 + l15;
      #pragma unroll
      for (int rr = 0; rr < 4; ++rr) {
        stage[(l4*4 + rr)*C_ + c] = acc0[o6][rr];
        stage[(16 + l4*4 + rr)*C_ + c] = acc1[o6][rr];
      }
    }
    __syncthreads();
    #pragma unroll 1
    for (int tile = 0; tile < 2; ++tile) {
      for (int s2 = t; s2 < 768; s2 += 256) {
        int cc = s2 >> 6, lp = s2 & 63;
        int n_l = lp & 15, l4g = lp >> 4;
        int c0 = cc*32 + l4g*8;
        u16 hh[8], ll[8];
        #pragma unroll
        for (int e = 0; e < 8; ++e)
          split_hl(stage[(tile*16 + n_l)*C_ + c0 + e], hh[e], ll[e]);
        size_t fo = ((size_t)(qb*2 + tile)*12 + cc)*512 + (size_t)lp*8;
        *(ushort4*)&qhi[fo] = make_ushort4(hh[0],hh[1],hh[2],hh[3]);
        *(ushort4*)&qhi[fo+4] = make_ushort4(hh[4],hh[5],hh[6],hh[7]);
        *(ushort4*)&qlo[fo] = make_ushort4(ll[0],ll[1],ll[2],ll[3]);
        *(ushort4*)&qlo[fo+4] = make_ushort4(ll[4],ll[5],ll[6],ll[7]);
      }
    }
  }
}

// ---------------- K3: MFMA router: 32-n tile, 4 waves = 4 kp-quarters x 2 n-tiles ----------------
__global__ __launch_bounds__(256, 2) void k_route(
    const u16* __restrict__ qhi, const u16* __restrict__ qlo,
    const u16* __restrict__ khi, const u16* __restrict__ klo,
    const u16* __restrict__ vthi,
    const u16* __restrict__ spt,
    const u16* __restrict__ mshi,
    const float* __restrict__ mask_parent, const float* __restrict__ node_mask,
    float* __restrict__ out, u16* __restrict__ pf,
    float* __restrict__ mu0, float* __restrict__ sigpc) {
  __shared__ u16   wlds[32*512];        // 32 KB, XOR-swizzled rows
  __shared__ float smask[KP];           // 2 KB
  __shared__ float red[4][2][2][16];    // 1 KB
  __shared__ float musred[4][2][64][4]; // 8 KB

  int t = threadIdx.x;
  int blk = blockIdx.x;                  // 0..511
  int swz = (blk & 7) * 64 + (blk >> 3); // XCD-aware
  int bb = swz >> 7;
  int nb = (swz & 127) * 32;
  int wh = t >> 6, lane = t & 63;
  int l15 = lane & 15, l4 = lane >> 4;

  {
    const float4* ms = (const float4*)(mask_parent + (size_t)bb*KP);
    for (int i = t; i < 128; i += 256) ((float4*)smask)[i] = ms[i];
  }
  __syncthreads();

  const u16* qhB0 = qhi + ((size_t)(bb*256 + (nb >> 4)))*12*512;
  const u16* qlB0 = qlo + ((size_t)(bb*256 + (nb >> 4)))*12*512;
  const u16* qhB1 = qhB0 + 12*512;
  const u16* qlB1 = qlB0 + 12*512;
  const u16* khB = khi + ((size_t)(bb*32 + wh*8))*12*512;
  const u16* klB = klo + ((size_t)(bb*32 + wh*8))*12*512;
  f4v acc0[8], acc1[8];
  #pragma unroll
  for (int kt = 0; kt < 8; ++kt) {
    acc0[kt] = (f4v){0.f,0.f,0.f,0.f};
    acc1[kt] = (f4v){0.f,0.f,0.f,0.f};
  }
  #pragma unroll 2
  for (int cs = 0; cs < 12; ++cs) {
    s8v bqh0 = *(const s8v*)&qhB0[(size_t)cs*512 + lane*8];
    s8v bql0 = *(const s8v*)&qlB0[(size_t)cs*512 + lane*8];
    s8v bqh1 = *(const s8v*)&qhB1[(size_t)cs*512 + lane*8];
    s8v bql1 = *(const s8v*)&qlB1[(size_t)cs*512 + lane*8];
    #pragma unroll
    for (int kt = 0; kt < 8; ++kt) {
      s8v ah = *(const s8v*)&khB[((size_t)kt*12 + cs)*512 + lane*8];
      s8v al = *(const s8v*)&klB[((size_t)kt*12 + cs)*512 + lane*8];
      acc0[kt] = MFMA(ah, bqh0, acc0[kt]);
      acc0[kt] = MFMA(ah, bql0, acc0[kt]);
      acc0[kt] = MFMA(al, bqh0, acc0[kt]);
      acc1[kt] = MFMA(ah, bqh1, acc1[kt]);
      acc1[kt] = MFMA(ah, bql1, acc1[kt]);
      acc1[kt] = MFMA(al, bqh1, acc1[kt]);
    }
  }

  float mx0 = -3.4e38f, mx1 = -3.4e38f;
  #pragma unroll
  for (int kt = 0; kt < 8; ++kt) {
    const float4 m4 = *(const float4*)&smask[wh*128 + kt*16 + l4*4];
    acc0[kt][0] = (m4.x > 0.5f) ? acc0[kt][0]*TAU_INV : NEGV;
    acc0[kt][1] = (m4.y > 0.5f) ? acc0[kt][1]*TAU_INV : NEGV;
    acc0[kt][2] = (m4.z > 0.5f) ? acc0[kt][2]*TAU_INV : NEGV;
    acc0[kt][3] = (m4.w > 0.5f) ? acc0[kt][3]*TAU_INV : NEGV;
    acc1[kt][0] = (m4.x > 0.5f) ? acc1[kt][0]*TAU_INV : NEGV;
    acc1[kt][1] = (m4.y > 0.5f) ? acc1[kt][1]*TAU_INV : NEGV;
    acc1[kt][2] = (m4.z > 0.5f) ? acc1[kt][2]*TAU_INV : NEGV;
    acc1[kt][3] = (m4.w > 0.5f) ? acc1[kt][3]*TAU_INV : NEGV;
    mx0 = fmaxf(mx0, fmaxf(fmaxf(acc0[kt][0], acc0[kt][1]), fmaxf(acc0[kt][2], acc0[kt][3])));
    mx1 = fmaxf(mx1, fmaxf(fmaxf(acc1[kt][0], acc1[kt][1]), fmaxf(acc1[kt][2], acc1[kt][3])));
  }
  mx0 = fmaxf(mx0, __shfl_xor(mx0, 16));
  mx0 = fmaxf(mx0, __shfl_xor(mx0, 32));
  mx1 = fmaxf(mx1, __shfl_xor(mx1, 16));
  mx1 = fmaxf(mx1, __shfl_xor(mx1, 32));
  if (lane < 16) { red[wh][0][0][lane] = mx0; red[wh][1][0][lane] = mx1; }
  __syncthreads();
  mx0 = fmaxf(fmaxf(red[0][0][0][l15], red[1][0][0][l15]),
              fmaxf(red[2][0][0][l15], red[3][0][0][l15]));
  mx1 = fmaxf(fmaxf(red[0][1][0][l15], red[1][1][0][l15]),
              fmaxf(red[2][1][0][l15], red[3][1][0][l15]));
  float sm0 = 0.f, sm1 = 0.f;
  #pragma unroll
  for (int kt = 0; kt < 8; ++kt) {
    #pragma unroll
    for (int r = 0; r < 4; ++r) {
      float e0 = __expf(acc0[kt][r] - mx0);
      float e1 = __expf(acc1[kt][r] - mx1);
      acc0[kt][r] = e0; sm0 += e0;
      acc1[kt][r] = e1; sm1 += e1;
    }
  }
  sm0 += __shfl_xor(sm0, 16); sm0 += __shfl_xor(sm0, 32);
  sm1 += __shfl_xor(sm1, 16); sm1 += __shfl_xor(sm1, 32);
  if (lane < 16) { red[wh][0][1][lane] = sm0; red[wh][1][1][lane] = sm1; }
  __syncthreads();
  sm0 = red[0][0][1][l15] + red[1][0][1][l15] + red[2][0][1][l15] + red[3][0][1][l15];
  sm1 = red[0][1][1][l15] + red[1][1][1][l15] + red[2][1][1][l15] + red[3][1][1][l15];
  float nm0 = node_mask[(size_t)bb*N_ + nb + l15];
  float nm1 = node_mask[(size_t)bb*N_ + nb + 16 + l15];
  float scl0 = nm0 / sm0, scl1 = nm1 / sm1;
  bool uni0 = !(nm0 > 0.5f), uni1 = !(nm1 > 0.5f);
  float uv0 = nm0 * (1.0f/KP), uv1 = nm1 * (1.0f/KP);
  #pragma unroll
  for (int kt = 0; kt < 8; ++kt) {
    int kpl = wh*128 + kt*16 + l4*4;
    ushort4 wv0, wv1;
    wv0.x = f2b_rne(uni0 ? uv0 : acc0[kt][0]*scl0);
    wv0.y = f2b_rne(uni0 ? uv0 : acc0[kt][1]*scl0);
    wv0.z = f2b_rne(uni0 ? uv0 : acc0[kt][2]*scl0);
    wv0.w = f2b_rne(uni0 ? uv0 : acc0[kt][3]*scl0);
    wv1.x = f2b_rne(uni1 ? uv1 : acc1[kt][0]*scl1);
    wv1.y = f2b_rne(uni1 ? uv1 : acc1[kt][1]*scl1);
    wv1.z = f2b_rne(uni1 ? uv1 : acc1[kt][2]*scl1);
    wv1.w = f2b_rne(uni1 ? uv1 : acc1[kt][3]*scl1);
    int bo0 = (l15*1024 + kpl*2) ^ ((l15 & 7) << 4);
    int bo1 = ((l15+16)*1024 + kpl*2) ^ ((l15 & 7) << 4);
    *(ushort4*)&wlds[bo0 >> 1] = wv0;
    *(ushort4*)&wlds[bo1 >> 1] = wv1;
  }
  __syncthreads();

  for (int ct = 0; ct < 6; ++ct) {
    int c_tile = wh*6 + ct;
    int c = c_tile*16 + l15;
    f4v aS0 = (f4v){0.f,0.f,0.f,0.f}, aS1 = aS0;
    f4v aP0 = aS0, aP1 = aS0;
    const u16* vhB = vthi + (((size_t)bb*24 + c_tile)*16)*512;
    const u16* spB = spt  + (((size_t)bb*24 + c_tile)*16)*512;
    #pragma unroll
    for (int ks = 0; ks < 16; ++ks) {
      int kp = ks*32 + l4*8;
      int bo0 = (l15*1024 + kp*2) ^ ((l15 & 7) << 4);
      int bo1 = ((l15+16)*1024 + kp*2) ^ ((l15 & 7) << 4);
      s8v aw0 = *(const s8v*)&wlds[bo0 >> 1];
      s8v aw1 = *(const s8v*)&wlds[bo1 >> 1];
      s8v bh = *(const s8v*)&vhB[(size_t)ks*512 + lane*8];
      s8v bs = *(const s8v*)&spB[(size_t)ks*512 + lane*8];
      aS0 = MFMA(aw0, bh, aS0);
      aP0 = MFMA(aw0, bs, aP0);
      aS1 = MFMA(aw1, bh, aS1);
      aP1 = MFMA(aw1, bs, aP1);
    }
    #pragma unroll
    for (int r = 0; r < 4; ++r) {
      int n0r = nb + l4*4 + r;
      int n1r = n0r + 16;
      size_t row0_ = (size_t)bb*N_ + n0r;
      size_t row1_ = (size_t)bb*N_ + n1r;
      out[row0_*396 + c] = aS0[r];
      out[row1_*396 + c] = aS1[r];
      pf[row0_*C_ + c] = f2b_rne(aP0[r]);
      pf[row1_*C_ + c] = f2b_rne(aP1[r]);
    }
  }

  // tail: single-precision musig (error ~0.002, within budget)
  {
    f4v p0 = (f4v){0.f,0.f,0.f,0.f}, p1 = p0;
    #pragma unroll
    for (int k2 = 0; k2 < 4; ++k2) {
      int ks = wh*4 + k2;
      int kp = ks*32 + l4*8;
      int bo0 = (l15*1024 + kp*2) ^ ((l15 & 7) << 4);
      int bo1 = ((l15+16)*1024 + kp*2) ^ ((l15 & 7) << 4);
      s8v aw0 = *(const s8v*)&wlds[bo0 >> 1];
      s8v aw1 = *(const s8v*)&wlds[bo1 >> 1];
      s8v bh = *(const s8v*)&mshi[(((size_t)bb*16 + ks)*64 + lane)*8];
      p0 = MFMA(aw0, bh, p0);
      p1 = MFMA(aw1, bh, p1);
    }
    #pragma unroll
    for (int r = 0; r < 4; ++r) {
      musred[wh][0][lane][r] = p0[r];
      musred[wh][1][lane][r] = p1[r];
    }
  }
  __syncthreads();
  if (wh < 2) {
    int tile = wh;
    int col = l15;
    #pragma unroll
    for (int r = 0; r < 4; ++r) {
      float d = musred[0][tile][lane][r] + musred[1][tile][lane][r]
              + musred[2][tile][lane][r] + musred[3][tile][lane][r];
      int n = nb + tile*16 + l4*4 + r;
      size_t row = (size_t)bb*N_ + n;
      if (col < 3) {
        mu0[row*3 + col] = d;
      } else if (col < 12) {
        int e = col - 3;
        if (e == 0 || e == 4 || e == 8) d += JITTER_;
        sigpc[row*9 + e] = d;
      }
    }
  }
}

// ---------------- K4: mu-offset MLP (MFMA, 32 rows/block, single-precision h) ----------------
__global__ __launch_bounds__(256) void k_mlp(
    const u16* __restrict__ pf, const float* __restrict__ g,
    const float* __restrict__ bb,
    const u16* __restrict__ w1hi,
    const float* __restrict__ b1, const float* __restrict__ W2,
    const float* __restrict__ b2v, const float* __restrict__ node_mask,
    float* __restrict__ mu0) {
  __shared__ u16 fr[4*6144];   // x hi for 2 tiles (lo regions unused)
  float* stage = (float*)fr;   // overlays: h stage [32][384] f32
  int t = threadIdx.x;
  int row0 = blockIdx.x * 32;
  #pragma unroll 1
  for (int tile = 0; tile < 2; ++tile) {
    int r = t >> 4, l = t & 15;
    const u16* xr = pf + (size_t)(row0 + tile*16 + r) * C_;
    float xv[24]; float s = 0.f;
    #pragma unroll
    for (int j = 0; j < 24; ++j) { xv[j] = b2f(xr[l + 16*j]); s += xv[j]; }
    #pragma unroll
    for (int m = 1; m < 16; m <<= 1) s += __shfl_xor(s, m);
    float mean = s * (1.0f/C_);
    float vs = 0.f;
    #pragma unroll
    for (int j = 0; j < 24; ++j) { float d = xv[j]-mean; vs += d*d; }
    #pragma unroll
    for (int m = 1; m < 16; m <<= 1) vs += __shfl_xor(vs, m);
    float rs = 1.0f / sqrtf(vs * (1.0f/C_) + 1e-5f);
    #pragma unroll
    for (int j = 0; j < 24; ++j) {
      int c = l + 16*j;
      float xc = (xv[j]-mean)*rs*g[c] + bb[c];
      int idx = (c >> 5)*512 + ((r & 15) + 16*((c >> 3) & 3))*8 + (c & 7);
      fr[tile*12288 + idx] = f2b_rne(xc);
    }
  }
  __syncthreads();
  int wv_ = t >> 6, lane = t & 63;
  int l15 = lane & 15, l4 = lane >> 4;
  f4v acc0[6], acc1[6];
  #pragma unroll
  for (int i = 0; i < 6; ++i) {
    acc0[i] = (f4v){0.f,0.f,0.f,0.f};
    acc1[i] = (f4v){0.f,0.f,0.f,0.f};
  }
  for (int cs = 0; cs < 12; ++cs) {
    s8v ah0 = *(const s8v*)&fr[cs*512 + lane*8];
    s8v ah1 = *(const s8v*)&fr[12288 + cs*512 + lane*8];
    #pragma unroll
    for (int o6 = 0; o6 < 6; ++o6) {
      int ot = wv_*6 + o6;
      s8v bh = *(const s8v*)&w1hi[((size_t)ot*12 + cs)*512 + lane*8];
      acc0[o6] = MFMA(ah0, bh, acc0[o6]);
      acc1[o6] = MFMA(ah1, bh, acc1[o6]);
    }
  }
  __syncthreads();
  #pragma unroll
  for (int o6 = 0; o6 < 6; ++o6) {
    int c = (wv_*6 + o6)*16 + l15;
    float bv = b1[c];
    #pragma unroll
    for (int rr = 0; rr < 4; ++rr) {
      float v0 = acc0[o6][rr] + bv;
      stage[(l4*4 + rr)*C_ + c] = v0 / (1.0f + __expf(-v0));
      float v1 = acc1[o6][rr] + bv;
      stage[(16 + l4*4 + rr)*C_ + c] = v1 / (1.0f + __expf(-v1));
    }
  }
  __syncthreads();
  #pragma unroll 1
  for (int tile = 0; tile < 2; ++tile) {
    int r = t >> 4, l = t & 15;
    const float* hr = &stage[(tile*16 + r)*C_];
    float pd0=0.f, pd1=0.f, pd2=0.f;
    #pragma unroll
    for (int j=0;j<24;++j) {
      int c = l + 16*j;
      float hv = hr[c];
      pd0 += hv*W2[c];
      pd1 += hv*W2[C_ + c];
      pd2 += hv*W2[2*C_ + c];
    }
    #pragma unroll
    for (int m = 1; m < 16; m <<= 1) {
      pd0 += __shfl_xor(pd0, m);
      pd1 += __shfl_xor(pd1, m);
      pd2 += __shfl_xor(pd2, m);
    }
    if (l == 0) {
      size_t row = (size_t)(row0 + tile*16 + r);
      float nmv = node_mask[row];
      float d0 = (pd0 + b2v[0]) * MU_SCALE_;
      float d1 = (pd1 + b2v[1]) * MU_SCALE_;
      float d2 = (pd2 + b2v[2]) * MU_SCALE_;
      mu0[row*3+0] = (mu0[row*3+0] + d0) * nmv;
      mu0[row*3+1] = (mu0[row*3+1] + d1) * nmv;
      mu0[row*3+2] = (mu0[row*3+2] + d2) * nmv;
    }
  }
}

// ---------------- K5: kNN sigma + Sig0 + mu0 out ----------------
__global__ __launch_bounds__(512, 4) void k_knn(
    const float* __restrict__ mu0, const float* __restrict__ node_mask,
    const float* __restrict__ sigpc, float* __restrict__ out) {
  __shared__ float4 cand[N_];
  int t = threadIdx.x;
  int b = blockIdx.y;
  int n0 = blockIdx.x * 32;
  const float* mb = mu0 + (size_t)b*N_*3;
  const float* nmB = node_mask + (size_t)b*N_;
  for (int idx = t; idx < N_; idx += 512) {
    float x = mb[idx*3+0], y = mb[idx*3+1], z = mb[idx*3+2];
    float w = (nmB[idx] > 0.5f) ? 0.f : BIG_;
    cand[idx] = make_float4(x, y, z, w);
  }
  __syncthreads();
  int r = t >> 4, qq = t & 15;
  int n = n0 + r;
  float4 e = cand[n];
  float best[8];
  #pragma unroll
  for (int i=0;i<8;++i) best[i] = BIG_;
  int base = qq * 256;
  #pragma unroll 4
  for (int i = 0; i < 256; ++i) {
    int m = base + ((i + qq) & 255);
    float4 c = cand[m];
    float dx = c.x - e.x, dy = c.y - e.y, dz = c.z - e.z;
    float d2 = dx*dx + dy*dy + dz*dz + c.w;
    if (m == n) d2 = BIG_;
    if (d2 < best[7]) {
      #pragma unroll
      for (int i2 = 7; i2 >= 1; --i2)
        best[i2] = (best[i2] > d2) ? ((best[i2-1] > d2) ? best[i2-1] : d2) : best[i2];
      best[0] = (best[0] > d2) ? d2 : best[0];
    }
  }
  #pragma unroll
  for (int mk = 1; mk <= 8; mk <<= 1) {
    float ob[8];
    #pragma unroll
    for (int i = 0; i < 8; ++i) ob[i] = __shfl_xor(best[7-i], mk);
    #pragma unroll
    for (int i = 0; i < 8; ++i) best[i] = fminf(best[i], ob[i]);
    #pragma unroll
    for (int i = 0; i < 4; ++i) {
      float lo = fminf(best[i], best[i+4]);
      float hi = fmaxf(best[i], best[i+4]);
      best[i] = lo; best[i+4] = hi;
    }
    #pragma unroll
    for (int gI = 0; gI < 2; ++gI) {
      int o = gI*4;
      float lo0 = fminf(best[o+0], best[o+2]);
      float hi0 = fmaxf(best[o+0], best[o+2]);
      float lo1 = fminf(best[o+1], best[o+3]);
      float hi1 = fmaxf(best[o+1], best[o+3]);
      best[o+0]=lo0; best[o+2]=hi0; best[o+1]=lo1; best[o+3]=hi1;
    }
    #pragma unroll
    for (int p = 0; p < 8; p += 2) {
      float lo = fminf(best[p], best[p+1]);
      float hi = fmaxf(best[p], best[p+1]);
      best[p] = lo; best[p+1] = hi;
    }
  }
  if (qq == 0) {
    float ssum = 0.f;
    #pragma unroll
    for (int i = 0; i < 8; ++i) ssum += sqrtf(fmaxf(best[i], 0.f));
    float sigma = fminf(fmaxf(ALPHA_ * (ssum * 0.125f), SFLOOR_), SCEIL_);
    float s2 = sigma*sigma + JITTER_;
    size_t row = (size_t)b*N_ + n;
    float nmv = nmB[n];
    size_t orow = row * 396;
    const float* sg = &sigpc[row*9];
    #pragma unroll
    for (int e2=0;e2<9;++e2) {
      bool diag = (e2==0)||(e2==4)||(e2==8);
      float v = BETA_*sg[e2] + (diag ? ((1.0f-BETA_)*s2 + JITTER_) : 0.0f);
      out[orow + 387 + e2] = v * nmv;
    }
    out[orow + 384] = e.x;
    out[orow + 385] = e.y;
    out[orow + 386] = e.z;
  }
}

extern "C" void kernel_launch(void* const* d_in, const int* in_sizes, int n_in,
                              void* d_out, int out_size, void* d_ws, size_t ws_size,
                              hipStream_t stream) {
  const float* s_parent    = (const float*)d_in[0];
  const float* mu_p        = (const float*)d_in[1];
  const float* Sig_p       = (const float*)d_in[2];
  const float* mask_parent = (const float*)d_in[3];
  const float* node_mask   = (const float*)d_in[4];
  const float* s_trunk     = (const float*)d_in[5];
  const float* Wq   = (const float*)d_in[6];
  const float* Wk   = (const float*)d_in[7];
  const float* Wv   = (const float*)d_in[8];
  const float* Wpos = (const float*)d_in[9];
  const float* lnq_g = (const float*)d_in[10];
  const float* lnq_b = (const float*)d_in[11];
  const float* lnk_g = (const float*)d_in[12];
  const float* lnk_b = (const float*)d_in[13];
  const float* lnv_g = (const float*)d_in[14];
  const float* lnv_b = (const float*)d_in[15];
  const float* mo_ln_g = (const float*)d_in[16];
  const float* mo_ln_b = (const float*)d_in[17];
  const float* mo_W1 = (const float*)d_in[18];
  const float* mo_b1 = (const float*)d_in[19];
  const float* mo_W2 = (const float*)d_in[20];
  const float* mo_b2 = (const float*)d_in[21];

  char* wsb = (char*)d_ws;
  u16* qhi  = (u16*)wsb;
  u16* qlo  = qhi + (size_t)B_*N_*C_;
  u16* khi  = (u16*)(wsb + 25165824);
  u16* klo  = khi + (size_t)B_*KP*C_;
  u16* vthi = (u16*)(wsb + 25165824 + 3145728);
  char* pfb = wsb + 25165824 + 2*3145728;
  u16* pf   = (u16*)pfb;
  u16* spt  = (u16*)(pfb + 12582912);
  char* pw  = pfb + 12582912 + 1572864;
  u16* wqhi  = (u16*)pw;                         // 294912 B each
  u16* wqlo  = (u16*)(pw + 294912);
  u16* wkhi  = (u16*)(pw + 589824);
  u16* wklo  = (u16*)(pw + 884736);
  u16* wvhi  = (u16*)(pw + 1179648);
  u16* mshi  = (u16*)(pw + 1769472);             // 65536 B
  u16* w1hi  = (u16*)(pw + 1900544);             // 294912 B
  float* mu0 = (float*)(wsb + 25165824 + 2*3145728 + 25165824);
  float* sg  = mu0 + (size_t)B_*N_*3;
  float* out = (float*)d_out;

  k_prep<<<dim3(868), dim3(256), 0, stream>>>(
      Wq, Wk, Wv, mo_W1, s_parent, mu_p, Sig_p,
      wqhi, wqlo, wkhi, wklo, wvhi, w1hi,
      spt, mshi);
  k_kq<<<dim3(640), dim3(256), 0, stream>>>(
      s_parent, mu_p, lnk_g, lnk_b, lnv_g, lnv_b,
      wkhi, wklo, wvhi, Wpos,
      khi, klo, vthi,
      s_trunk, lnq_g, lnq_b, wqhi, wqlo, qhi, qlo);
  k_route<<<dim3(512), dim3(256), 0, stream>>>(
      qhi, qlo, khi, klo, vthi, spt, mshi,
      mask_parent, node_mask, out, pf, mu0, sg);
  k_mlp<<<dim3(B_*N_/32), dim3(256), 0, stream>>>(
      pf, mo_ln_g, mo_ln_b, w1hi, mo_b1, mo_W2, mo_b2, node_mask, mu0);
  k_knn<<<dim3(N_/32, B_), dim3(512), 0, stream>>>(
      mu0, node_mask, sg, out);
}